// Round 1
// baseline (258.920 us; speedup 1.0000x reference)
//
#include <hip/hip_runtime.h>

#define N 4096
#define D 1024
#define BM 128
#define BN 128
#define BK 32

typedef __bf16 bf16x8 __attribute__((ext_vector_type(8)));
typedef float floatx4 __attribute__((ext_vector_type(4)));

__device__ __forceinline__ ushort f2bf(float f) {
    union { float f; uint32_t u; } c; c.f = f;
    uint32_t u = c.u;
    uint32_t r = u + 0x7FFFu + ((u >> 16) & 1u);
    return (ushort)(r >> 16);
}

// ---------------------------------------------------------------------------
// Kernel 1: fp32 -> bf16 conversion + per-row squared norm (fp32 exact form)
// ---------------------------------------------------------------------------
__global__ __launch_bounds__(256) void prep_kernel(const float* __restrict__ x,
                                                   ushort* __restrict__ xb,
                                                   float* __restrict__ sq) {
    int row = blockIdx.x;
    int tid = threadIdx.x;   // 256 threads, one float4 each (D=1024)
    float4 v = ((const float4*)(x + (size_t)row * D))[tid];
    float s = v.x * v.x + v.y * v.y + v.z * v.z + v.w * v.w;
    ushort4 b = make_ushort4(f2bf(v.x), f2bf(v.y), f2bf(v.z), f2bf(v.w));
    ((ushort4*)(xb + (size_t)row * D))[tid] = b;

    #pragma unroll
    for (int sh = 1; sh < 64; sh <<= 1) s += __shfl_xor(s, sh);
    __shared__ float wsum[4];
    int lane = tid & 63, w = tid >> 6;
    if (lane == 0) wsum[w] = s;
    __syncthreads();
    if (tid == 0) sq[row] = wsum[0] + wsum[1] + wsum[2] + wsum[3];
}

// ---------------------------------------------------------------------------
// Kernel 2: fused X.X^T GEMM (bf16 MFMA) + dist + masked exp row-reductions
// rowAcc[i][0..5] = pos_logit, neg_logit, pos_b, neg_b, pos_d, neg_d
// ---------------------------------------------------------------------------
__global__ __launch_bounds__(256, 2) void gemm_fused(const ushort* __restrict__ xb,
                                                     const float* __restrict__ sq,
                                                     float* __restrict__ rowAcc) {
    __shared__ ushort smem[2 * BM * BK];   // As [128][32] then Bs [128][32]

    const int bi = blockIdx.y, bj = blockIdx.x;
    const int i0 = bi * BM, j0 = bj * BN;
    const int tid = threadIdx.x;
    const int lane = tid & 63, wave = tid >> 6;
    const int wm = wave >> 1, wn = wave & 1;        // 2x2 waves over 128x128
    const int quad = lane >> 4, c16 = lane & 15;

    floatx4 acc[4][4];
    #pragma unroll
    for (int a = 0; a < 4; ++a)
        #pragma unroll
        for (int b = 0; b < 4; ++b) acc[a][b] = (floatx4){0.f, 0.f, 0.f, 0.f};

    for (int kt = 0; kt < D; kt += BK) {
        // ---- stage A(128x32) + B(128x32) bf16 via global_load_lds x16B ----
        #pragma unroll
        for (int it = 0; it < 4; ++it) {
            int chunk = it * 256 + tid;          // 1024 chunks of 16B
            int half = chunk >> 9;               // 0 = A, 1 = B (wave-uniform)
            int c = chunk & 511;
            int row = c >> 2, kc = c & 3;
            int grow = (half ? j0 : i0) + row;
            const ushort* gp = xb + (size_t)grow * D + kt + kc * 8;
            ushort* lp = smem + chunk * 8;       // 16B per chunk, lane-contiguous
            __builtin_amdgcn_global_load_lds(
                (const __attribute__((address_space(1))) void*)gp,
                (__attribute__((address_space(3))) void*)lp, 16, 0, 0);
        }
        __syncthreads();   // drains vmcnt -> LDS tiles ready

        bf16x8 afrag[4], bfrag[4];
        #pragma unroll
        for (int t = 0; t < 4; ++t) {
            afrag[t] = *(const bf16x8*)(smem + ((wm * 64 + t * 16 + c16) * BK + quad * 8));
            bfrag[t] = *(const bf16x8*)(smem + BM * BK + ((wn * 64 + t * 16 + c16) * BK + quad * 8));
        }
        #pragma unroll
        for (int tm = 0; tm < 4; ++tm)
            #pragma unroll
            for (int tn = 0; tn < 4; ++tn)
                acc[tm][tn] = __builtin_amdgcn_mfma_f32_16x16x32_bf16(
                    afrag[tm], bfrag[tn], acc[tm][tn], 0, 0, 0);
        __syncthreads();   // protect LDS before next stage overwrites
    }

    // ---- fused epilogue: dist -> exp terms -> per-row reduction -> atomics ----
    // C/D layout: col = lane&15, row = quad*4 + reg   [measured m89/m91]
    #pragma unroll
    for (int tm = 0; tm < 4; ++tm) {
        #pragma unroll
        for (int r = 0; r < 4; ++r) {
            const int gi = i0 + wm * 64 + tm * 16 + quad * 4 + r;
            const float sqi = sq[gi];
            float pa = 0.f, na = 0.f, pb = 0.f, nb = 0.f, pd = 0.f, nd = 0.f;
            #pragma unroll
            for (int tn = 0; tn < 4; ++tn) {
                const int gj = j0 + wn * 64 + tn * 16 + c16;
                float dot = acc[tm][tn][r];
                float dsq = sqi + sq[gj] - 2.0f * dot;
                float dist = sqrtf(fmaxf(dsq, 1e-12f));
                float t = __expf(20.0f * (1.1f - dist));          // neg exp term
                bool same = (gi >> 3) == (gj >> 3);
                if (same) {
                    if (gi != gj) {
                        pa += t * t * 0.018315638888734179f;      // exp(40(1-d))
                        pb += 403.4287934927351f * __builtin_amdgcn_rcpf(t); // exp(20(d-0.8))
                        pd += dist;
                    }
                } else {
                    na += t * t * 0.018315638888734179f;
                    nb += t;
                    nd += dist;
                }
            }
            // reduce the 16 lanes of this quad (they hold the row's 64 cols w/ tn)
            #pragma unroll
            for (int s = 1; s < 16; s <<= 1) {
                pa += __shfl_xor(pa, s); na += __shfl_xor(na, s);
                pb += __shfl_xor(pb, s); nb += __shfl_xor(nb, s);
                pd += __shfl_xor(pd, s); nd += __shfl_xor(nd, s);
            }
            if (c16 == 0) {
                float* rp = rowAcc + (size_t)gi * 6;
                atomicAdd(rp + 0, pa); atomicAdd(rp + 1, na);
                atomicAdd(rp + 2, pb); atomicAdd(rp + 3, nb);
                atomicAdd(rp + 4, pd); atomicAdd(rp + 5, nd);
            }
        }
    }
}

// ---------------------------------------------------------------------------
// Kernel 3: per-row loss assembly + global means
// ---------------------------------------------------------------------------
__global__ __launch_bounds__(256) void finalize_kernel(const float* __restrict__ rowAcc,
                                                       float* __restrict__ out) {
    int tid = threadIdx.x;
    float lsum = 0.f, pdsum = 0.f, ndsum = 0.f;
    for (int i = tid; i < N; i += 256) {
        const float* rp = rowAcc + (size_t)i * 6;
        float pa = rp[0], na = rp[1], pb = rp[2], nb = rp[3];
        float a_lr = 1.0f - pa / (pa + na);
        lsum += a_lr * (logf(pb) + logf(nb));
        pdsum += rp[4];
        ndsum += rp[5];
    }
    #pragma unroll
    for (int s = 1; s < 64; s <<= 1) {
        lsum += __shfl_xor(lsum, s);
        pdsum += __shfl_xor(pdsum, s);
        ndsum += __shfl_xor(ndsum, s);
    }
    __shared__ float r0[4], r1[4], r2[4];
    int lane = tid & 63, w = tid >> 6;
    if (lane == 0) { r0[w] = lsum; r1[w] = pdsum; r2[w] = ndsum; }
    __syncthreads();
    if (tid == 0) {
        float L = r0[0] + r0[1] + r0[2] + r0[3];
        float P = r1[0] + r1[1] + r1[2] + r1[3];
        float Ng = r2[0] + r2[1] + r2[2] + r2[3];
        out[0] = L / (float)N;
        out[1] = 0.0f;                                   // accuracy never incremented
        out[2] = P / ((float)N * 7.0f);                  // pos pairs per row = 7
        out[3] = Ng / ((float)N * (float)(N - 8));       // neg pairs per row = 4088
    }
}

// ---------------------------------------------------------------------------
extern "C" void kernel_launch(void* const* d_in, const int* in_sizes, int n_in,
                              void* d_out, int out_size, void* d_ws, size_t ws_size,
                              hipStream_t stream) {
    const float* x = (const float*)d_in[0];
    float* out = (float*)d_out;
    char* ws = (char*)d_ws;

    ushort* xb     = (ushort*)ws;                                  // 8 MB bf16 matrix
    float*  sq     = (float*)(ws + (size_t)N * D * 2);             // 16 KB row norms
    float*  rowAcc = (float*)(ws + (size_t)N * D * 2 + N * 4);     // 96 KB accumulators

    hipMemsetAsync(rowAcc, 0, (size_t)N * 6 * sizeof(float), stream);

    prep_kernel<<<N, 256, 0, stream>>>(x, xb, sq);

    dim3 grid(N / BN, N / BM);
    gemm_fused<<<grid, 256, 0, stream>>>(xb, sq, rowAcc);

    finalize_kernel<<<1, 256, 0, stream>>>(rowAcc, out);
}

// Round 2
// 122.543 us; speedup vs baseline: 2.1129x; 2.1129x over previous
//
#include <hip/hip_runtime.h>

#define N 4096
#define D 1024
#define BM 128
#define BN 128
#define BK 32
#define NSLOT 32   // N / BM partial-slots per column

typedef __bf16 bf16x8 __attribute__((ext_vector_type(8)));
typedef float floatx4 __attribute__((ext_vector_type(4)));

__device__ __forceinline__ ushort f2bf(float f) {
    union { float f; uint32_t u; } c; c.f = f;
    uint32_t u = c.u;
    uint32_t r = u + 0x7FFFu + ((u >> 16) & 1u);
    return (ushort)(r >> 16);
}

// ---------------------------------------------------------------------------
// Kernel 1: fp32 -> bf16 conversion + per-row squared norm (fp32 exact form)
// ---------------------------------------------------------------------------
__global__ __launch_bounds__(256) void prep_kernel(const float* __restrict__ x,
                                                   ushort* __restrict__ xb,
                                                   float* __restrict__ sq) {
    int row = blockIdx.x;
    int tid = threadIdx.x;   // 256 threads, one float4 each (D=1024)
    float4 v = ((const float4*)(x + (size_t)row * D))[tid];
    float s = v.x * v.x + v.y * v.y + v.z * v.z + v.w * v.w;
    ushort4 b = make_ushort4(f2bf(v.x), f2bf(v.y), f2bf(v.z), f2bf(v.w));
    ((ushort4*)(xb + (size_t)row * D))[tid] = b;

    #pragma unroll
    for (int sh = 1; sh < 64; sh <<= 1) s += __shfl_xor(s, sh);
    __shared__ float wsum[4];
    int lane = tid & 63, w = tid >> 6;
    if (lane == 0) wsum[w] = s;
    __syncthreads();
    if (tid == 0) sq[row] = wsum[0] + wsum[1] + wsum[2] + wsum[3];
}

// ---------------------------------------------------------------------------
// Kernel 2: fused X.X^T GEMM (bf16 MFMA) + dist + masked exp COLUMN-reductions
// (dist & masks are symmetric => column sums == row sums; columns are cheap
//  to reduce in the MFMA C/D layout: in-lane over tm,r then 2 shuffle steps)
// Atomic-free: block (bi,bj) writes partials to colPart[bi][j0..j0+127][6].
// ---------------------------------------------------------------------------
__global__ __launch_bounds__(256, 2) void gemm_fused(const ushort* __restrict__ xb,
                                                     const float* __restrict__ sq,
                                                     float* __restrict__ colPart) {
    __shared__ ushort smem[2 * BM * BK];   // As [128][32] then Bs [128][32]

    const int bi = blockIdx.y, bj = blockIdx.x;
    const int i0 = bi * BM, j0 = bj * BN;
    const int tid = threadIdx.x;
    const int lane = tid & 63, wave = tid >> 6;
    const int wm = wave >> 1, wn = wave & 1;        // 2x2 waves over 128x128
    const int quad = lane >> 4, c16 = lane & 15;

    floatx4 acc[4][4];
    #pragma unroll
    for (int a = 0; a < 4; ++a)
        #pragma unroll
        for (int b = 0; b < 4; ++b) acc[a][b] = (floatx4){0.f, 0.f, 0.f, 0.f};

    for (int kt = 0; kt < D; kt += BK) {
        // ---- stage A(128x32) + B(128x32) bf16 via global_load_lds x16B ----
        #pragma unroll
        for (int it = 0; it < 4; ++it) {
            int chunk = it * 256 + tid;          // 1024 chunks of 16B
            int half = chunk >> 9;               // 0 = A, 1 = B (wave-uniform)
            int c = chunk & 511;
            int row = c >> 2, kc = c & 3;
            int grow = (half ? j0 : i0) + row;
            const ushort* gp = xb + (size_t)grow * D + kt + kc * 8;
            ushort* lp = smem + chunk * 8;       // 16B per chunk, lane-contiguous
            __builtin_amdgcn_global_load_lds(
                (const __attribute__((address_space(1))) void*)gp,
                (__attribute__((address_space(3))) void*)lp, 16, 0, 0);
        }
        __syncthreads();   // drains vmcnt -> LDS tiles ready

        bf16x8 afrag[4], bfrag[4];
        #pragma unroll
        for (int t = 0; t < 4; ++t) {
            afrag[t] = *(const bf16x8*)(smem + ((wm * 64 + t * 16 + c16) * BK + quad * 8));
            bfrag[t] = *(const bf16x8*)(smem + BM * BK + ((wn * 64 + t * 16 + c16) * BK + quad * 8));
        }
        #pragma unroll
        for (int tm = 0; tm < 4; ++tm)
            #pragma unroll
            for (int tn = 0; tn < 4; ++tn)
                acc[tm][tn] = __builtin_amdgcn_mfma_f32_16x16x32_bf16(
                    afrag[tm], bfrag[tn], acc[tm][tn], 0, 0, 0);
        __syncthreads();   // protect LDS before next stage overwrites
    }

    // ---- epilogue: column partial sums (pa, na, pb, nb, pd, nd) ----
    // C/D layout: col = c16, row = quad*4 + r   [measured m89/m91]
    float sqi[4][4];
    #pragma unroll
    for (int tm = 0; tm < 4; ++tm)
        #pragma unroll
        for (int r = 0; r < 4; ++r)
            sqi[tm][r] = sq[i0 + wm * 64 + tm * 16 + quad * 4 + r];
    float sqj[4];
    #pragma unroll
    for (int tn = 0; tn < 4; ++tn)
        sqj[tn] = sq[j0 + wn * 64 + tn * 16 + c16];

    float cpa[4], cna[4], cpb[4], cnb[4], cpd[4], cnd[4];
    const bool diag = (bi == bj);   // same-class pairs only occur here (8 | 128)

    #pragma unroll
    for (int tn = 0; tn < 4; ++tn) {
        float pa = 0.f, na = 0.f, pb = 0.f, nb = 0.f, pd = 0.f, nd = 0.f;
        if (!diag) {
            // pure negatives: branch-free
            #pragma unroll
            for (int tm = 0; tm < 4; ++tm)
                #pragma unroll
                for (int r = 0; r < 4; ++r) {
                    float dot = acc[tm][tn][r];
                    float dsq = sqi[tm][r] + sqj[tn] - 2.0f * dot;
                    float dist = sqrtf(fmaxf(dsq, 1e-12f));
                    float t = __expf(20.0f * (1.1f - dist));   // exp(BETA*(1.1-d))
                    na = fmaf(t, t, na);                        // t^2 ~ exp(40(1-d))*e^4
                    nb += t;
                    nd += dist;
                }
        } else {
            const int gjc = (j0 + wn * 64 + tn * 16 + c16) >> 3;   // class of col
            const int gj = j0 + wn * 64 + tn * 16 + c16;
            #pragma unroll
            for (int tm = 0; tm < 4; ++tm)
                #pragma unroll
                for (int r = 0; r < 4; ++r) {
                    const int gi = i0 + wm * 64 + tm * 16 + quad * 4 + r;
                    float dot = acc[tm][tn][r];
                    float dsq = sqi[tm][r] + sqj[tn] - 2.0f * dot;
                    float dist = sqrtf(fmaxf(dsq, 1e-12f));
                    float t = __expf(20.0f * (1.1f - dist));
                    bool same = (gi >> 3) == gjc;
                    if (same) {
                        if (gi != gj) {
                            pa = fmaf(t, t, pa);
                            pb += __expf(20.0f * (dist - 0.8f));
                            pd += dist;
                        }
                    } else {
                        na = fmaf(t, t, na);
                        nb += t;
                        nd += dist;
                    }
                }
        }
        cpa[tn] = pa; cna[tn] = na; cpb[tn] = pb;
        cnb[tn] = nb; cpd[tn] = pd; cnd[tn] = nd;
    }

    // reduce the 4 quads (each column's 64 rows): lanes ^16, ^32 only
    #pragma unroll
    for (int tn = 0; tn < 4; ++tn) {
        #pragma unroll
        for (int s = 16; s < 64; s <<= 1) {
            cna[tn] += __shfl_xor(cna[tn], s);
            cnb[tn] += __shfl_xor(cnb[tn], s);
            cnd[tn] += __shfl_xor(cnd[tn], s);
        }
        if (diag) {
            #pragma unroll
            for (int s = 16; s < 64; s <<= 1) {
                cpa[tn] += __shfl_xor(cpa[tn], s);
                cpb[tn] += __shfl_xor(cpb[tn], s);
                cpd[tn] += __shfl_xor(cpd[tn], s);
            }
        }
    }

    // combine the two wm halves via LDS (smem is free after last barrier)
    float* colBuf = (float*)smem;   // [2][128][6] floats = 6 KB
    #pragma unroll
    for (int tn = 0; tn < 4; ++tn) {
        // all 4 quads hold identical reduced values; same-addr same-value writes
        int cb = (wm * 128 + wn * 64 + tn * 16 + c16) * 6;
        colBuf[cb + 0] = cpa[tn]; colBuf[cb + 1] = cna[tn];
        colBuf[cb + 2] = cpb[tn]; colBuf[cb + 3] = cnb[tn];
        colBuf[cb + 4] = cpd[tn]; colBuf[cb + 5] = cnd[tn];
    }
    __syncthreads();

    // atomic-free partial store: contiguous 3 KB per block
    float* dst = colPart + (size_t)bi * N * 6 + (size_t)j0 * 6;
    #pragma unroll
    for (int it = 0; it < 3; ++it) {
        int idx = it * 256 + tid;               // 0..767
        dst[idx] = colBuf[idx] + colBuf[768 + idx];
    }
}

// ---------------------------------------------------------------------------
// Kernel 3: reduce the 32 per-block partial slots -> per-row loss pieces
// ---------------------------------------------------------------------------
__global__ __launch_bounds__(256) void reduce_rows(const float* __restrict__ colPart,
                                                   float* __restrict__ rowOut) {
    int j = blockIdx.x * 256 + threadIdx.x;     // 4096 threads total
    float pa = 0.f, na = 0.f, pb = 0.f, nb = 0.f, pd = 0.f, nd = 0.f;
    for (int s = 0; s < NSLOT; ++s) {
        const float* p = colPart + (size_t)s * N * 6 + (size_t)j * 6;
        pa += p[0]; na += p[1]; pb += p[2];
        nb += p[3]; pd += p[4]; nd += p[5];
    }
    // pa/na both carry the same e^4 factor vs exp(40(1-d)) -> cancels in a_lr
    float a_lr = 1.0f - pa / (pa + na);
    rowOut[j * 3 + 0] = a_lr * (logf(pb) + logf(nb));
    rowOut[j * 3 + 1] = pd;
    rowOut[j * 3 + 2] = nd;
}

// ---------------------------------------------------------------------------
// Kernel 4: global means
// ---------------------------------------------------------------------------
__global__ __launch_bounds__(256) void finalize_kernel(const float* __restrict__ rowOut,
                                                       float* __restrict__ out) {
    int tid = threadIdx.x;
    float L = 0.f, P = 0.f, G = 0.f;
    for (int i = tid; i < N; i += 256) {
        L += rowOut[i * 3 + 0];
        P += rowOut[i * 3 + 1];
        G += rowOut[i * 3 + 2];
    }
    #pragma unroll
    for (int s = 1; s < 64; s <<= 1) {
        L += __shfl_xor(L, s);
        P += __shfl_xor(P, s);
        G += __shfl_xor(G, s);
    }
    __shared__ float r0[4], r1[4], r2[4];
    int lane = tid & 63, w = tid >> 6;
    if (lane == 0) { r0[w] = L; r1[w] = P; r2[w] = G; }
    __syncthreads();
    if (tid == 0) {
        float Ls = r0[0] + r0[1] + r0[2] + r0[3];
        float Ps = r1[0] + r1[1] + r1[2] + r1[3];
        float Gs = r2[0] + r2[1] + r2[2] + r2[3];
        out[0] = Ls / (float)N;
        out[1] = 0.0f;                                   // accuracy never incremented
        out[2] = Ps / ((float)N * 7.0f);                 // pos pairs per row = 7
        out[3] = Gs / ((float)N * (float)(N - 8));       // neg pairs per row = 4088
    }
}

// ---------------------------------------------------------------------------
extern "C" void kernel_launch(void* const* d_in, const int* in_sizes, int n_in,
                              void* d_out, int out_size, void* d_ws, size_t ws_size,
                              hipStream_t stream) {
    const float* x = (const float*)d_in[0];
    float* out = (float*)d_out;
    char* ws = (char*)d_ws;

    ushort* xb      = (ushort*)ws;                                   // 8 MB bf16 matrix
    float*  sq      = (float*)(ws + (size_t)N * D * 2);              // 16 KB row norms
    float*  colPart = (float*)(ws + (size_t)N * D * 2 + N * 4);      // 3 MB partials
    float*  rowOut  = (float*)(ws + (size_t)N * D * 2 + N * 4
                               + (size_t)NSLOT * N * 6 * 4);         // 48 KB

    prep_kernel<<<N, 256, 0, stream>>>(x, xb, sq);

    dim3 grid(N / BN, N / BM);
    gemm_fused<<<grid, 256, 0, stream>>>(xb, sq, colPart);

    reduce_rows<<<N / 256, 256, 0, stream>>>(colPart, rowOut);
    finalize_kernel<<<1, 256, 0, stream>>>(rowOut, out);
}